// Round 3
// baseline (608.255 us; speedup 1.0000x reference)
//
#include <hip/hip_runtime.h>
#include <stdint.h>

// Inputs (fp32, per reference):
//   core0: [1000][a=8][i=8][k=16]        float32
//   core1: [1000][k=16][c=8][j=8][m=16]  float32
//   core2: [1000][m=16][d=8][l=8]        float32
//   idx:   [512] int32
// Output: FLOAT32 [512][row=(a,c,d)=512][col=(i,j,l)=512]
// Block = one (b, a); grid = 512*8 = 4096; 256 threads.

__device__ __forceinline__ float bflo(uint32_t u) { return __uint_as_float(u << 16); }
__device__ __forceinline__ float bfhi(uint32_t u) { return __uint_as_float(u & 0xffff0000u); }
// pack two fp32 -> bf16 pair (round-half-up, max 0.5 ulp), pure shift/mask
__device__ __forceinline__ uint32_t pack_bf2(float f0, float f1) {
  uint32_t a = __float_as_uint(f0) + 0x8000u;
  uint32_t b = __float_as_uint(f1) + 0x8000u;
  return (a >> 16) | (b & 0xffff0000u);
}

__global__ __launch_bounds__(256) void tt_stack_kernel(
    const float* __restrict__ c0f,
    const float* __restrict__ c1f,
    const float* __restrict__ c2f,
    const int* __restrict__ idx,
    float* __restrict__ outf)
{
  __shared__ __align__(16) uint32_t lds_c1[8192];  // bf16 pairs [k][c][j][m/2]  32 KB
  __shared__ __align__(16) float    lds_c0[128];   // fp32 [i][k]                0.5 KB
  __shared__ __align__(16) float    lds_c2[1024];  // fp32 [m][d][l]             4 KB
  __shared__ __align__(16) uint32_t lds_t[4096];   // bf16 pairs [(c,i,j)][m/2] 16 KB

  const int tid = threadIdx.x;
  const int bid = blockIdx.x;
  const int b = bid >> 3;
  const int a = bid & 7;
  const int s = idx[b];

  // ---- stage c1: fp32 global -> bf16 pairs in LDS, coalesced float4 ----
  {
    const float4* src4 = (const float4*)(c1f + (size_t)s * 16384);
#pragma unroll
    for (int r = 0; r < 16; ++r) {
      const float4 v = src4[r * 256 + tid];
      uint2* dst = (uint2*)&lds_c1[2 * (r * 256 + tid)];
      *dst = make_uint2(pack_bf2(v.x, v.y), pack_bf2(v.z, v.w));
    }
  }
  // ---- c0 row for this a, fp32 ----
  if (tid < 128) lds_c0[tid] = c0f[(size_t)(s * 8 + a) * 128 + tid];
  // ---- c2 fp32 ----
#pragma unroll
  for (int r = 0; r < 4; ++r) lds_c2[r * 256 + tid] = c2f[(size_t)s * 1024 + r * 256 + tid];
  __syncthreads();

  // ---- step 1: t[c,i,j,m] = sum_k c0[i,k] * c1[k,c,j,m]; 2 rows/thread ----
#pragma unroll
  for (int cc = 0; cc < 2; ++cc) {
    const int combo = tid + cc * 256;      // (c,i,j)
    const int c = combo >> 6;
    const int i = (combo >> 3) & 7;
    const int j = combo & 7;
    float a_k[16];
#pragma unroll
    for (int k = 0; k < 16; ++k) a_k[k] = lds_c0[i * 16 + k];
    float acc[16];
#pragma unroll
    for (int m = 0; m < 16; ++m) acc[m] = 0.f;
#pragma unroll
    for (int k = 0; k < 16; ++k) {
      const uint4* rp = (const uint4*)&lds_c1[((k * 8 + c) * 8 + j) * 8];
      const uint4 u0 = rp[0];
      const uint4 u1 = rp[1];
      const float av = a_k[k];
      acc[0]  = fmaf(av, bflo(u0.x), acc[0]);   acc[1]  = fmaf(av, bfhi(u0.x), acc[1]);
      acc[2]  = fmaf(av, bflo(u0.y), acc[2]);   acc[3]  = fmaf(av, bfhi(u0.y), acc[3]);
      acc[4]  = fmaf(av, bflo(u0.z), acc[4]);   acc[5]  = fmaf(av, bfhi(u0.z), acc[5]);
      acc[6]  = fmaf(av, bflo(u0.w), acc[6]);   acc[7]  = fmaf(av, bfhi(u0.w), acc[7]);
      acc[8]  = fmaf(av, bflo(u1.x), acc[8]);   acc[9]  = fmaf(av, bfhi(u1.x), acc[9]);
      acc[10] = fmaf(av, bflo(u1.y), acc[10]);  acc[11] = fmaf(av, bfhi(u1.y), acc[11]);
      acc[12] = fmaf(av, bflo(u1.z), acc[12]);  acc[13] = fmaf(av, bfhi(u1.z), acc[13]);
      acc[14] = fmaf(av, bflo(u1.w), acc[14]);  acc[15] = fmaf(av, bfhi(u1.w), acc[15]);
    }
    uint4* tp = (uint4*)&lds_t[combo * 8];
    tp[0] = make_uint4(pack_bf2(acc[0],  acc[1]),  pack_bf2(acc[2],  acc[3]),
                       pack_bf2(acc[4],  acc[5]),  pack_bf2(acc[6],  acc[7]));
    tp[1] = make_uint4(pack_bf2(acc[8],  acc[9]),  pack_bf2(acc[10], acc[11]),
                       pack_bf2(acc[12], acc[13]), pack_bf2(acc[14], acc[15]));
  }
  __syncthreads();

  // ---- step 2: out[(c,d),(i,j,l)] = sum_m t[c,i,j,m] * c2[m,d,l] ----
  // thread owns (d, l-quad); c2 slice lives in 64 registers, read once.
  const int g = tid & 15;      // (d, lh)
  const int d = g >> 1;
  const int lh = g & 1;
  const int set = tid >> 4;    // 16 row-sets
  float c2r[16][4];
#pragma unroll
  for (int m = 0; m < 16; ++m) {
    const float4 v = *(const float4*)&lds_c2[m * 64 + d * 8 + lh * 4];
    c2r[m][0] = v.x; c2r[m][1] = v.y; c2r[m][2] = v.z; c2r[m][3] = v.w;
  }
  float* outb = outf + (size_t)b * 262144 + (size_t)a * 32768;  // float units
  for (int rr = 0; rr < 32; ++rr) {
    const int row = rr * 16 + set;   // (c,i,j)
    const int c = row >> 6;
    const int i = (row >> 3) & 7;
    const int j = row & 7;
    const uint4* tp = (const uint4*)&lds_t[row * 8];
    const uint4 t0 = tp[0];
    const uint4 t1 = tp[1];
    float tm[16];
    tm[0]=bflo(t0.x); tm[1]=bfhi(t0.x); tm[2]=bflo(t0.y); tm[3]=bfhi(t0.y);
    tm[4]=bflo(t0.z); tm[5]=bfhi(t0.z); tm[6]=bflo(t0.w); tm[7]=bfhi(t0.w);
    tm[8]=bflo(t1.x); tm[9]=bfhi(t1.x); tm[10]=bflo(t1.y); tm[11]=bfhi(t1.y);
    tm[12]=bflo(t1.z); tm[13]=bfhi(t1.z); tm[14]=bflo(t1.w); tm[15]=bfhi(t1.w);
    float acc4[4] = {0.f, 0.f, 0.f, 0.f};
#pragma unroll
    for (int m = 0; m < 16; ++m) {
      acc4[0] = fmaf(tm[m], c2r[m][0], acc4[0]);
      acc4[1] = fmaf(tm[m], c2r[m][1], acc4[1]);
      acc4[2] = fmaf(tm[m], c2r[m][2], acc4[2]);
      acc4[3] = fmaf(tm[m], c2r[m][3], acc4[3]);
    }
    float4* dst = (float4*)(outb + ((c * 8 + d) << 9) + i * 64 + j * 8 + lh * 4);
    *dst = make_float4(acc4[0], acc4[1], acc4[2], acc4[3]);
  }
}

extern "C" void kernel_launch(void* const* d_in, const int* in_sizes, int n_in,
                              void* d_out, int out_size, void* d_ws, size_t ws_size,
                              hipStream_t stream) {
  const float* c0f = (const float*)d_in[0];
  const float* c1f = (const float*)d_in[1];
  const float* c2f = (const float*)d_in[2];
  const int* idx = (const int*)d_in[3];
  float* outf = (float*)d_out;
  const int B = in_sizes[3];  // 512
  dim3 grid(B * 8), block(256);
  hipLaunchKernelGGL(tt_stack_kernel, grid, block, 0, stream, c0f, c1f, c2f, idx, outf);
}